// Round 12
// baseline (330.631 us; speedup 1.0000x reference)
//
#include <hip/hip_runtime.h>
#include <hip/hip_fp16.h>

// GCN 3->32->32->1, N=100K, E=6.4M (+self loops).
// R19 closure: k_l2's 73us == 440MB through the per-CU vector-load path at
//   ~9.1 B/cyc/CU (the same ~6.3TB/s ceiling as streaming; m13). Request
//   count (R17), L2 residency (R9/R12), dep chains (R15) all falsified;
//   BYTES are the only lever.
// R20: shrink bytes. (a) g table -> uint8 + per-row fp32 scale (g is
//   post-ReLU, non-negative -> full u8 range; scale=rowmax/255). Row 64->
//   32B; k_l2 vector bytes 440->~265MB; table 3.6MB -> L2-resident so the
//   HBM co-ceiling disappears. Dequant: cvt_f32_ubyte + fma (VALU has
//   headroom). (b) y table -> fp16 8B rows: k_l1 gather 102->51MB.
//   Precision: +u8 quant error ~3-5e-4 absmax predicted; fallback = revert
//   (a) keep (b) if the harness threshold bites.
// Carried: LDS W2/b2/W3 epilogue, int4 csr, 4 acc banks, fused k_sort,
//   hist-row-differencing k_bsort, zero global atomics, 256B carves.

#define BLK 256
#define BLK2 512         // k_bsort / k_sort / k_scanA block size
#define SB 1600          // chunks; SB*CHUNK == E exactly
#define CHUNK 4000
#define BKT 128          // nodes per bucket
#define NBKT 782         // ceil(100000/128)
#define MAXNB 1024       // scanB width >= NBKT
#define BUFSZ 9950       // k_sort bucket buffer (mean 8192 + 19.4 sigma)

// ---- pass 1: per-chunk histogram over dst buckets (LDS, int4 loads)
__global__ void k_hist(const int* __restrict__ dst, int* __restrict__ hist, int E) {
    __shared__ int lh[NBKT];
    for (int b = threadIdx.x; b < NBKT; b += blockDim.x) lh[b] = 0;
    __syncthreads();
    int beg = blockIdx.x * CHUNK;
    int end = min(E, beg + CHUNK);
    int nq = (end - beg) >> 2;                    // full int4 quads
    const int4* d4 = (const int4*)(dst + beg);
    for (int i = threadIdx.x; i < nq; i += blockDim.x) {
        int4 d = d4[i];
        atomicAdd(&lh[d.x >> 7], 1);
        atomicAdd(&lh[d.y >> 7], 1);
        atomicAdd(&lh[d.z >> 7], 1);
        atomicAdd(&lh[d.w >> 7], 1);
    }
    for (int e = beg + (nq << 2) + threadIdx.x; e < end; e += blockDim.x)
        atomicAdd(&lh[dst[e] >> 7], 1);
    __syncthreads();
    for (int b = threadIdx.x; b < NBKT; b += blockDim.x)
        hist[(size_t)blockIdx.x * NBKT + b] = lh[b];
}

// ---- scan A: per bucket, exclusive-scan its SB chunk-counts
// (512 threads x 4 guarded items = 2048 >= SB=1600)
__global__ void k_scanA(int* __restrict__ hist, int* __restrict__ btot, int NB) {
    int b = blockIdx.x, t = threadIdx.x;
    int base = t * 4;
    int v0 = (base + 0 < SB) ? hist[(size_t)(base + 0) * NB + b] : 0;
    int v1 = (base + 1 < SB) ? hist[(size_t)(base + 1) * NB + b] : 0;
    int v2 = (base + 2 < SB) ? hist[(size_t)(base + 2) * NB + b] : 0;
    int v3 = (base + 3 < SB) ? hist[(size_t)(base + 3) * NB + b] : 0;
    int s = v0 + v1 + v2 + v3;
    int lane = t & 63, w = t >> 6;
    int x = s;
#pragma unroll
    for (int off = 1; off < 64; off <<= 1) {
        int u = __shfl_up(x, off, 64);
        if (lane >= off) x += u;
    }
    __shared__ int wsum[8];
    if (lane == 63) wsum[w] = x;
    __syncthreads();
    int woff = 0;
    for (int k = 0; k < 8; k++) woff += (k < w) ? wsum[k] : 0;
    int run = woff + x - s;                       // exclusive prefix for item 0
    if (base + 0 < SB) hist[(size_t)(base + 0) * NB + b] = run;  run += v0;
    if (base + 1 < SB) hist[(size_t)(base + 1) * NB + b] = run;  run += v1;
    if (base + 2 < SB) hist[(size_t)(base + 2) * NB + b] = run;  run += v2;
    if (base + 3 < SB) hist[(size_t)(base + 3) * NB + b] = run;  run += v3;
    if (t == 511) btot[b] = run;
}

// ---- scan B: exclusive-scan bucket totals -> bucket base offsets
__global__ void k_scanB(const int* __restrict__ btot, int* __restrict__ bbase,
                        int NB, int E) {
    __shared__ int sh[MAXNB];
    int t = threadIdx.x;
    int v = (t < NB) ? btot[t] : 0;
    sh[t] = v;
    __syncthreads();
    for (int off = 1; off < MAXNB; off <<= 1) {
        int u = (t >= off) ? sh[t - off] : 0;
        __syncthreads();
        sh[t] += u;
        __syncthreads();
    }
    if (t < NB) bbase[t] = sh[t] - v;
    if (t == 0) bbase[NB] = E;
}

// ---- pass 2: LDS chunk-sort by bucket, full-lane sorted-order streaming.
__global__ void k_bsort(const int* __restrict__ src, const int* __restrict__ dst,
                        const int* __restrict__ hist, const int* __restrict__ btot,
                        const int* __restrict__ bbase,
                        unsigned int* __restrict__ packed, int E) {
    __shared__ unsigned int bufB[CHUNK];          // 16 KB
    __shared__ unsigned short binarr2[CHUNK];     // 8 KB (bucket of sorted pos)
    __shared__ int cnt[NBKT];
    __shared__ int off[NBKT];
    __shared__ int cur[NBKT];
    __shared__ int gbase[NBKT];
    __shared__ int wsum[8];
    int t = threadIdx.x;
    int beg = blockIdx.x * CHUNK;
    int end = min(E, beg + CHUNK);
    int len = end - beg;
    int last = (blockIdx.x + 1 == gridDim.x);
    for (int b = t; b < NBKT; b += blockDim.x) {
        int my = hist[(size_t)blockIdx.x * NBKT + b];
        int nx = last ? btot[b] : hist[(size_t)(blockIdx.x + 1) * NBKT + b];
        cnt[b] = nx - my;
        gbase[b] = bbase[b] + my;
    }
    __syncthreads();
    // phase b: exclusive scan of 782 counts (2 items/thread, shfl, 8 waves)
    {
        int base = t * 2;
        int v0 = (base + 0 < NBKT) ? cnt[base + 0] : 0;
        int v1 = (base + 1 < NBKT) ? cnt[base + 1] : 0;
        int s = v0 + v1;
        int lane = t & 63, w = t >> 6;
        int x = s;
#pragma unroll
        for (int o = 1; o < 64; o <<= 1) {
            int u = __shfl_up(x, o, 64);
            if (lane >= o) x += u;
        }
        if (lane == 63) wsum[w] = x;
        __syncthreads();
        int woff = 0;
        for (int k = 0; k < 8; k++) woff += (k < w) ? wsum[k] : 0;
        int run = woff + x - s;
        if (base + 0 < NBKT) { off[base + 0] = run; cur[base + 0] = run; } run += v0;
        if (base + 1 < NBKT) { off[base + 1] = run; cur[base + 1] = run; } run += v1;
    }
    __syncthreads();
    // phase c: permute into bucket-grouped order
    for (int i = t; i < len; i += blockDim.x) {
        int d = dst[beg + i];
        int s = src[beg + i];
        int b = d >> 7;
        int pos = atomicAdd(&cur[b], 1);
        bufB[pos] = (unsigned)s | ((unsigned)(d & 127) << 17);
        binarr2[pos] = (unsigned short)b;
    }
    __syncthreads();
    // phase d: full-lane sorted-order write (runs are dest-contiguous)
    for (int i = t; i < len; i += blockDim.x) {
        int b = binarr2[i];
        packed[gbase[b] + i - off[b]] = bufB[i];
    }
}

// ---- fused: per-bucket 128-bin count + scan + dis/y8/rowptr + in-place
// node sort. 512 threads, fused load+count. y stored as 4 fp16 (8B).
__global__ void k_sort(unsigned int* __restrict__ packed, const int* __restrict__ bbase,
                       const float* __restrict__ x, float* __restrict__ dis,
                       uint2* __restrict__ y8, int* __restrict__ rowptr, int N, int E) {
    __shared__ unsigned int buf[BUFSZ];           // 38.9 KB
    __shared__ int cnt[BKT];
    __shared__ int cur[BKT];
    __shared__ int wsum[2];
    int b = blockIdx.x, t = threadIdx.x;
    int beg = bbase[b], end = bbase[b + 1];
    int len = end - beg;
    if (t < BKT) cnt[t] = 0;
    __syncthreads();
    // fused: load bucket into LDS + count bins in one pass
    for (int i = t; i < len; i += blockDim.x) {
        unsigned v = packed[beg + i];
        buf[i] = v;
        atomicAdd(&cnt[v >> 17], 1);
    }
    __syncthreads();
    // exclusive scan over 128 bins (threads 0..127, 2 waves)
    int v0 = 0, xs = 0;
    if (t < BKT) {
        v0 = cnt[t];
        xs = v0;
#pragma unroll
        for (int o = 1; o < 64; o <<= 1) {
            int u = __shfl_up(xs, o, 64);
            if ((t & 63) >= o) xs += u;
        }
        if ((t & 63) == 63) wsum[t >> 6] = xs;
    }
    __syncthreads();
    if (t < BKT) {
        int woff = (t >= 64) ? wsum[0] : 0;
        int excl = woff + xs - v0;
        cur[t] = excl;
        int gi = b * BKT + t;
        if (gi < N) {
            rowptr[gi] = beg + excl;
            float di = rsqrtf((float)v0 + 1.0f);  // + self loop
            dis[gi] = di;
            uint2 yv;
            *(__half2*)&yv.x = __floats2half2_rn(di * x[3 * gi + 0],
                                                 di * x[3 * gi + 1]);
            *(__half2*)&yv.y = __floats2half2_rn(di * x[3 * gi + 2], 0.f);
            y8[gi] = yv;
        }
    }
    __syncthreads();
    for (int i = t; i < len; i += blockDim.x) {
        unsigned vv = buf[i];
        int pos = atomicAdd(&cur[vv >> 17], 1);   // LDS atomic
        packed[beg + pos] = vv & 0x1FFFF;         // plain src id, node-sorted
    }
    if (b == 0 && t == 0) rowptr[N] = E;
}

// ---- layer 1: node-parallel, 32 lanes/node gather y8 (0.8MB, L2-resident);
// writes u8-quantized g rows (gi, 32B/row) + per-row fp32 scale (gs).
__global__ void k_l1(const unsigned int* __restrict__ csr, const int* __restrict__ rowptr,
                     const uint2* __restrict__ y8, const float* __restrict__ dis,
                     const float* __restrict__ W1, const float* __restrict__ b1,
                     unsigned char* __restrict__ gi8, float* __restrict__ gs, int N) {
    int t = blockIdx.x * blockDim.x + threadIdx.x;
    int i = t >> 5, j = t & 31;
    if (i >= N) return;
    int beg = rowptr[i], end = rowptr[i + 1];
    float ax = 0.f, ay = 0.f, az = 0.f;
    for (int e = beg + j; e < end; e += 32) {
        uint2 v = y8[csr[e]];
        float2 fa = __half22float2(*(const __half2*)&v.x);
        float2 fb = __half22float2(*(const __half2*)&v.y);
        ax += fa.x; ay += fa.y; az += fb.x;
    }
#pragma unroll
    for (int m = 16; m >= 1; m >>= 1) {
        ax += __shfl_xor(ax, m, 32);
        ay += __shfl_xor(ay, m, 32);
        az += __shfl_xor(az, m, 32);
    }
    float di = dis[i];
    uint2 vs = y8[i];                                // self loop (pre-scaled)
    float2 sa = __half22float2(*(const __half2*)&vs.x);
    float2 sb = __half22float2(*(const __half2*)&vs.y);
    float a0 = di * (ax + sa.x);
    float a1 = di * (ay + sa.y);
    float a2 = di * (az + sb.x);
    float h = b1[j] + a0 * W1[j] + a1 * W1[32 + j] + a2 * W1[64 + j];
    float val = di * fmaxf(h, 0.f);                  // >= 0
    // per-row max over 32 lanes -> u8 quantization
    float mv = val;
#pragma unroll
    for (int m = 16; m >= 1; m >>= 1)
        mv = fmaxf(mv, __shfl_xor(mv, m, 32));
    float inv = (mv > 0.f) ? 255.0f / mv : 0.f;
    gi8[(size_t)i * 32 + j] = (unsigned char)__float2uint_rn(val * inv);
    if (j == 0) gs[i] = mv * (1.0f / 255.0f);
}

// dequant-accumulate 4 u8 features with row scale (v_cvt_f32_ubyteN + fma)
__device__ __forceinline__ void accq(float& c0, float& c1, float& c2, float& c3,
                                     unsigned r, float sc) {
    c0 = fmaf(sc, (float)(r & 0xffu), c0);
    c1 = fmaf(sc, (float)((r >> 8) & 0xffu), c1);
    c2 = fmaf(sc, (float)((r >> 16) & 0xffu), c2);
    c3 = fmaf(sc, (float)(r >> 24), c3);
}

// ---- layer 2 (+L3 projection): 8 lanes/node, lane j owns features 4j..4j+3.
// Per edge: 4B u8x4 gather per lane (8 lanes = 32B row) + broadcast 4B scale.
// Tables gi(3.2MB)+gs(0.4MB) are per-XCD-L2-resident. 4 acc banks; int4 csr;
// LDS W2/b2/W3 epilogue.
__global__ void k_l2(const unsigned int* __restrict__ csr, const int* __restrict__ rowptr,
                     const unsigned int* __restrict__ gi4, const float* __restrict__ gs,
                     const float* __restrict__ dis,
                     const float* __restrict__ W2, const float* __restrict__ b2,
                     const float* __restrict__ W3, float* __restrict__ q, int N) {
    __shared__ float sW2[1024];                      // 4KB: [32 in][32 out]
    __shared__ float sb2[32];
    __shared__ float sW3[32];
    int tid = threadIdx.x;
    ((float4*)sW2)[tid] = ((const float4*)W2)[tid];  // 256 thr x 16B = 4KB
    if (tid < 32) { sb2[tid] = b2[tid]; sW3[tid] = W3[tid]; }
    __syncthreads();
    int t = blockIdx.x * blockDim.x + tid;
    int i = t >> 3, j = t & 7;
    if (i >= N) return;
    int beg = rowptr[i], end = rowptr[i + 1];
    float pa0 = 0.f, pa1 = 0.f, pa2 = 0.f, pa3 = 0.f;   // bank A
    float pb0 = 0.f, pb1 = 0.f, pb2 = 0.f, pb3 = 0.f;   // bank B
    float pc0 = 0.f, pc1 = 0.f, pc2 = 0.f, pc3 = 0.f;   // bank C
    float pd0 = 0.f, pd1 = 0.f, pd2 = 0.f, pd3 = 0.f;   // bank D
    int e = beg;
    // head-peel to 4-edge (16B) alignment for int4 csr loads
    for (; e < end && (e & 3); e++) {
        int s = (int)csr[e];
        accq(pa0, pa1, pa2, pa3, gi4[s * 8 + j], gs[s]);
    }
    for (; e + 8 <= end; e += 8) {
        int4 ca = *(const int4*)(csr + e);           // slots 0..3 (aligned)
        int4 cb = *(const int4*)(csr + e + 4);       // slots 4..7
        unsigned r0 = gi4[ca.x * 8 + j]; float s0 = gs[ca.x];
        unsigned r1 = gi4[ca.y * 8 + j]; float s1 = gs[ca.y];
        unsigned r2 = gi4[ca.z * 8 + j]; float s2 = gs[ca.z];
        unsigned r3 = gi4[ca.w * 8 + j]; float s3 = gs[ca.w];
        unsigned r4 = gi4[cb.x * 8 + j]; float s4 = gs[cb.x];
        unsigned r5 = gi4[cb.y * 8 + j]; float s5 = gs[cb.y];
        unsigned r6 = gi4[cb.z * 8 + j]; float s6 = gs[cb.z];
        unsigned r7 = gi4[cb.w * 8 + j]; float s7 = gs[cb.w];
        accq(pa0, pa1, pa2, pa3, r0, s0);
        accq(pb0, pb1, pb2, pb3, r1, s1);
        accq(pc0, pc1, pc2, pc3, r2, s2);
        accq(pd0, pd1, pd2, pd3, r3, s3);
        accq(pa0, pa1, pa2, pa3, r4, s4);
        accq(pb0, pb1, pb2, pb3, r5, s5);
        accq(pc0, pc1, pc2, pc3, r6, s6);
        accq(pd0, pd1, pd2, pd3, r7, s7);
    }
    for (; e < end; e++) {
        int s = (int)csr[e];
        accq(pa0, pa1, pa2, pa3, gi4[s * 8 + j], gs[s]);
    }
    float c0 = (pa0 + pb0) + (pc0 + pd0);
    float c1 = (pa1 + pb1) + (pc1 + pd1);
    float c2 = (pa2 + pb2) + (pc2 + pd2);
    float c3 = (pa3 + pb3) + (pc3 + pd3);
    float di = dis[i];
    unsigned rs = gi4[i * 8 + j];                    // self-loop slice (dequant)
    float ssc = gs[i];
    float a0 = di * (c0 + ssc * (float)(rs & 0xffu));
    float a1 = di * (c1 + ssc * (float)((rs >> 8) & 0xffu));
    float a2 = di * (c2 + ssc * (float)((rs >> 16) & 0xffu));
    float a3 = di * (c3 + ssc * (float)(rs >> 24));
    // W2 matmul from LDS: lane j -> outputs m=4j..4j+3
    int m = 4 * j;
    float4 bo = *(const float4*)&sb2[m];
    float o0 = bo.x, o1 = bo.y, o2 = bo.z, o3 = bo.w;
#pragma unroll
    for (int kl = 0; kl < 8; kl++) {
        float x0 = __shfl(a0, kl, 8);                // a[4kl+0]
        float x1 = __shfl(a1, kl, 8);
        float x2 = __shfl(a2, kl, 8);
        float x3 = __shfl(a3, kl, 8);
        float4 w0 = *(const float4*)&sW2[(4 * kl + 0) * 32 + m];
        float4 w1 = *(const float4*)&sW2[(4 * kl + 1) * 32 + m];
        float4 w2 = *(const float4*)&sW2[(4 * kl + 2) * 32 + m];
        float4 w3 = *(const float4*)&sW2[(4 * kl + 3) * 32 + m];
        o0 = fmaf(x0, w0.x, fmaf(x1, w1.x, fmaf(x2, w2.x, fmaf(x3, w3.x, o0))));
        o1 = fmaf(x0, w0.y, fmaf(x1, w1.y, fmaf(x2, w2.y, fmaf(x3, w3.y, o1))));
        o2 = fmaf(x0, w0.z, fmaf(x1, w1.z, fmaf(x2, w2.z, fmaf(x3, w3.z, o2))));
        o3 = fmaf(x0, w0.w, fmaf(x1, w1.w, fmaf(x2, w2.w, fmaf(x3, w3.w, o3))));
    }
    float4 wv = *(const float4*)&sW3[m];
    float cc = fmaxf(o0, 0.f) * wv.x + fmaxf(o1, 0.f) * wv.y
             + fmaxf(o2, 0.f) * wv.z + fmaxf(o3, 0.f) * wv.w;
    cc += __shfl_xor(cc, 1, 8);
    cc += __shfl_xor(cc, 2, 8);
    cc += __shfl_xor(cc, 4, 8);
    if (j == 0) q[i] = di * cc;                      // q = dis * p
}

// ---- layer 3: node-parallel scalar q gathers (q 400KB, L2-resident)
__global__ void k_l3(const unsigned int* __restrict__ csr, const int* __restrict__ rowptr,
                     const float* __restrict__ q, const float* __restrict__ dis,
                     const float* __restrict__ b3, float* __restrict__ out, int N) {
    int t = blockIdx.x * blockDim.x + threadIdx.x;
    int i = t >> 5, j = t & 31;
    if (i >= N) return;
    int beg = rowptr[i], end = rowptr[i + 1];
    float acc = 0.f;
    for (int e = beg + j; e < end; e += 32)
        acc += q[csr[e]];
#pragma unroll
    for (int m = 16; m >= 1; m >>= 1)
        acc += __shfl_xor(acc, m, 32);
    if (j == 0) out[i] = dis[i] * (acc + q[i]) + b3[0];
}

extern "C" void kernel_launch(void* const* d_in, const int* in_sizes, int n_in,
                              void* d_out, int out_size, void* d_ws, size_t ws_size,
                              hipStream_t stream) {
    const float* x  = (const float*)d_in[0];
    const int*   ei = (const int*)d_in[1];
    const float* W1 = (const float*)d_in[2];
    const float* b1 = (const float*)d_in[3];
    const float* W2 = (const float*)d_in[4];
    const float* b2 = (const float*)d_in[5];
    const float* W3 = (const float*)d_in[6];
    const float* b3 = (const float*)d_in[7];
    float* out = (float*)d_out;

    int N = in_sizes[0] / 3;
    int E = in_sizes[1] / 2;
    const int* src = ei;
    const int* dst = ei + E;

    // workspace (all init done in-kernel; no memset needed), 256B-aligned carves
    char* w = (char*)d_ws;
#define CARVE(nbytes) w; w += (((size_t)(nbytes) + 255) & ~(size_t)255)
    int*   hist   = (int*)  CARVE((size_t)SB * NBKT * 4);   // 5.0 MB
    int*   btot   = (int*)  CARVE((size_t)MAXNB * 4);
    int*   bbase  = (int*)  CARVE((size_t)(MAXNB + 1) * 4);
    int*   rowptr = (int*)  CARVE((size_t)(N + 1) * 4);
    float* dis    = (float*)CARVE((size_t)N * 4);
    uint2* y8     = (uint2*)CARVE((size_t)N * 8);           // fp16 x4 per node
    unsigned char* gi8 = (unsigned char*)CARVE((size_t)N * 32);  // 3.2 MB u8
    float* gs     = (float*)CARVE((size_t)N * 4);           // per-row scale
    float* q      = (float*)CARVE((size_t)N * 4);
    unsigned int* packed = (unsigned int*)CARVE((size_t)E * 4);  // 25.6 MB
#undef CARVE

    k_hist <<<SB, BLK, 0, stream>>>(dst, hist, E);
    k_scanA<<<NBKT, BLK2, 0, stream>>>(hist, btot, NBKT);
    k_scanB<<<1, MAXNB, 0, stream>>>(btot, bbase, NBKT, E);
    k_bsort<<<SB, BLK2, 0, stream>>>(src, dst, hist, btot, bbase, packed, E);
    k_sort <<<NBKT, BLK2, 0, stream>>>(packed, bbase, x, dis, y8, rowptr, N, E);

    long long tn = (long long)N * 32;
    unsigned gn = (unsigned)((tn + BLK - 1) / BLK);
    long long tn8 = (long long)N * 8;
    unsigned gn8 = (unsigned)((tn8 + BLK - 1) / BLK);
    k_l1<<<gn,  BLK, 0, stream>>>(packed, rowptr, y8, dis, W1, b1, gi8, gs, N);
    k_l2<<<gn8, BLK, 0, stream>>>(packed, rowptr, (const unsigned int*)gi8, gs,
                                  dis, W2, b2, W3, q, N);
    k_l3<<<gn,  BLK, 0, stream>>>(packed, rowptr, q, dis, b3, out, N);
}

// Round 14
// 324.650 us; speedup vs baseline: 1.0184x; 1.0184x over previous
//
#include <hip/hip_runtime.h>
#include <hip/hip_fp16.h>

// GCN 3->32->32->1, N=100K, E=6.4M (+self loops).
// R20 verdict: BYTES falsified as k_l2's bound (u8 g: bytes -40%, FETCH
//   216->70MB, time 73->80us). Surviving model: PER-ITERATION LATENCY
//   STALL — each 8-edge iter issues loads then stalls ~450cyc on vmcnt;
//   ~5 waves/SIMD x ~50cyc work can't hide it (390 iters x 450cyc ~= the
//   observed 175K cyc/CU). Explains R15/R17 nulls and R20's regression
//   (gs loads added waitcnt slots). k_l1 gained ~3us from fp16 y — kept.
// R21: halve stalls/edge — 16-edge unroll (4x int4 csr + 16 gathers +
//   16 acc4 per iter). +32 VGPR (~68), occupancy 32->28 waves/CU, minor
//   vs 2x stall amortization. g reverted to fp16.
//   Discriminator: ~50-58us => model right; ~72 => k_l2 at HW floor.
// R22: resubmit of R21 unchanged — round 13 died to container infra
//   failure (no measurement; kernel re-audited: bounds/alignment sound).
// Carried: fp16 g + fp16 y8, LDS W2/b2/W3 epilogue, int4 csr, 4 acc
//   banks, fused k_sort, hist-row-differencing k_bsort, zero global
//   atomics, 256B carves.

#define BLK 256
#define BLK2 512         // k_bsort / k_sort / k_scanA block size
#define SB 1600          // chunks; SB*CHUNK == E exactly
#define CHUNK 4000
#define BKT 128          // nodes per bucket
#define NBKT 782         // ceil(100000/128)
#define MAXNB 1024       // scanB width >= NBKT
#define BUFSZ 9950       // k_sort bucket buffer (mean 8192 + 19.4 sigma)

// ---- pass 1: per-chunk histogram over dst buckets (LDS, int4 loads)
__global__ void k_hist(const int* __restrict__ dst, int* __restrict__ hist, int E) {
    __shared__ int lh[NBKT];
    for (int b = threadIdx.x; b < NBKT; b += blockDim.x) lh[b] = 0;
    __syncthreads();
    int beg = blockIdx.x * CHUNK;
    int end = min(E, beg + CHUNK);
    int nq = (end - beg) >> 2;                    // full int4 quads
    const int4* d4 = (const int4*)(dst + beg);
    for (int i = threadIdx.x; i < nq; i += blockDim.x) {
        int4 d = d4[i];
        atomicAdd(&lh[d.x >> 7], 1);
        atomicAdd(&lh[d.y >> 7], 1);
        atomicAdd(&lh[d.z >> 7], 1);
        atomicAdd(&lh[d.w >> 7], 1);
    }
    for (int e = beg + (nq << 2) + threadIdx.x; e < end; e += blockDim.x)
        atomicAdd(&lh[dst[e] >> 7], 1);
    __syncthreads();
    for (int b = threadIdx.x; b < NBKT; b += blockDim.x)
        hist[(size_t)blockIdx.x * NBKT + b] = lh[b];
}

// ---- scan A: per bucket, exclusive-scan its SB chunk-counts
// (512 threads x 4 guarded items = 2048 >= SB=1600)
__global__ void k_scanA(int* __restrict__ hist, int* __restrict__ btot, int NB) {
    int b = blockIdx.x, t = threadIdx.x;
    int base = t * 4;
    int v0 = (base + 0 < SB) ? hist[(size_t)(base + 0) * NB + b] : 0;
    int v1 = (base + 1 < SB) ? hist[(size_t)(base + 1) * NB + b] : 0;
    int v2 = (base + 2 < SB) ? hist[(size_t)(base + 2) * NB + b] : 0;
    int v3 = (base + 3 < SB) ? hist[(size_t)(base + 3) * NB + b] : 0;
    int s = v0 + v1 + v2 + v3;
    int lane = t & 63, w = t >> 6;
    int x = s;
#pragma unroll
    for (int off = 1; off < 64; off <<= 1) {
        int u = __shfl_up(x, off, 64);
        if (lane >= off) x += u;
    }
    __shared__ int wsum[8];
    if (lane == 63) wsum[w] = x;
    __syncthreads();
    int woff = 0;
    for (int k = 0; k < 8; k++) woff += (k < w) ? wsum[k] : 0;
    int run = woff + x - s;                       // exclusive prefix for item 0
    if (base + 0 < SB) hist[(size_t)(base + 0) * NB + b] = run;  run += v0;
    if (base + 1 < SB) hist[(size_t)(base + 1) * NB + b] = run;  run += v1;
    if (base + 2 < SB) hist[(size_t)(base + 2) * NB + b] = run;  run += v2;
    if (base + 3 < SB) hist[(size_t)(base + 3) * NB + b] = run;  run += v3;
    if (t == 511) btot[b] = run;
}

// ---- scan B: exclusive-scan bucket totals -> bucket base offsets
__global__ void k_scanB(const int* __restrict__ btot, int* __restrict__ bbase,
                        int NB, int E) {
    __shared__ int sh[MAXNB];
    int t = threadIdx.x;
    int v = (t < NB) ? btot[t] : 0;
    sh[t] = v;
    __syncthreads();
    for (int off = 1; off < MAXNB; off <<= 1) {
        int u = (t >= off) ? sh[t - off] : 0;
        __syncthreads();
        sh[t] += u;
        __syncthreads();
    }
    if (t < NB) bbase[t] = sh[t] - v;
    if (t == 0) bbase[NB] = E;
}

// ---- pass 2: LDS chunk-sort by bucket, full-lane sorted-order streaming.
__global__ void k_bsort(const int* __restrict__ src, const int* __restrict__ dst,
                        const int* __restrict__ hist, const int* __restrict__ btot,
                        const int* __restrict__ bbase,
                        unsigned int* __restrict__ packed, int E) {
    __shared__ unsigned int bufB[CHUNK];          // 16 KB
    __shared__ unsigned short binarr2[CHUNK];     // 8 KB (bucket of sorted pos)
    __shared__ int cnt[NBKT];
    __shared__ int off[NBKT];
    __shared__ int cur[NBKT];
    __shared__ int gbase[NBKT];
    __shared__ int wsum[8];
    int t = threadIdx.x;
    int beg = blockIdx.x * CHUNK;
    int end = min(E, beg + CHUNK);
    int len = end - beg;
    int last = (blockIdx.x + 1 == gridDim.x);
    for (int b = t; b < NBKT; b += blockDim.x) {
        int my = hist[(size_t)blockIdx.x * NBKT + b];
        int nx = last ? btot[b] : hist[(size_t)(blockIdx.x + 1) * NBKT + b];
        cnt[b] = nx - my;
        gbase[b] = bbase[b] + my;
    }
    __syncthreads();
    // phase b: exclusive scan of 782 counts (2 items/thread, shfl, 8 waves)
    {
        int base = t * 2;
        int v0 = (base + 0 < NBKT) ? cnt[base + 0] : 0;
        int v1 = (base + 1 < NBKT) ? cnt[base + 1] : 0;
        int s = v0 + v1;
        int lane = t & 63, w = t >> 6;
        int x = s;
#pragma unroll
        for (int o = 1; o < 64; o <<= 1) {
            int u = __shfl_up(x, o, 64);
            if (lane >= o) x += u;
        }
        if (lane == 63) wsum[w] = x;
        __syncthreads();
        int woff = 0;
        for (int k = 0; k < 8; k++) woff += (k < w) ? wsum[k] : 0;
        int run = woff + x - s;
        if (base + 0 < NBKT) { off[base + 0] = run; cur[base + 0] = run; } run += v0;
        if (base + 1 < NBKT) { off[base + 1] = run; cur[base + 1] = run; } run += v1;
    }
    __syncthreads();
    // phase c: permute into bucket-grouped order
    for (int i = t; i < len; i += blockDim.x) {
        int d = dst[beg + i];
        int s = src[beg + i];
        int b = d >> 7;
        int pos = atomicAdd(&cur[b], 1);
        bufB[pos] = (unsigned)s | ((unsigned)(d & 127) << 17);
        binarr2[pos] = (unsigned short)b;
    }
    __syncthreads();
    // phase d: full-lane sorted-order write (runs are dest-contiguous)
    for (int i = t; i < len; i += blockDim.x) {
        int b = binarr2[i];
        packed[gbase[b] + i - off[b]] = bufB[i];
    }
}

// ---- fused: per-bucket 128-bin count + scan + dis/y8/rowptr + in-place
// node sort. 512 threads, fused load+count. y stored as 4 fp16 (8B).
__global__ void k_sort(unsigned int* __restrict__ packed, const int* __restrict__ bbase,
                       const float* __restrict__ x, float* __restrict__ dis,
                       uint2* __restrict__ y8, int* __restrict__ rowptr, int N, int E) {
    __shared__ unsigned int buf[BUFSZ];           // 38.9 KB
    __shared__ int cnt[BKT];
    __shared__ int cur[BKT];
    __shared__ int wsum[2];
    int b = blockIdx.x, t = threadIdx.x;
    int beg = bbase[b], end = bbase[b + 1];
    int len = end - beg;
    if (t < BKT) cnt[t] = 0;
    __syncthreads();
    // fused: load bucket into LDS + count bins in one pass
    for (int i = t; i < len; i += blockDim.x) {
        unsigned v = packed[beg + i];
        buf[i] = v;
        atomicAdd(&cnt[v >> 17], 1);
    }
    __syncthreads();
    // exclusive scan over 128 bins (threads 0..127, 2 waves)
    int v0 = 0, xs = 0;
    if (t < BKT) {
        v0 = cnt[t];
        xs = v0;
#pragma unroll
        for (int o = 1; o < 64; o <<= 1) {
            int u = __shfl_up(xs, o, 64);
            if ((t & 63) >= o) xs += u;
        }
        if ((t & 63) == 63) wsum[t >> 6] = xs;
    }
    __syncthreads();
    if (t < BKT) {
        int woff = (t >= 64) ? wsum[0] : 0;
        int excl = woff + xs - v0;
        cur[t] = excl;
        int gi = b * BKT + t;
        if (gi < N) {
            rowptr[gi] = beg + excl;
            float di = rsqrtf((float)v0 + 1.0f);  // + self loop
            dis[gi] = di;
            uint2 yv;
            *(__half2*)&yv.x = __floats2half2_rn(di * x[3 * gi + 0],
                                                 di * x[3 * gi + 1]);
            *(__half2*)&yv.y = __floats2half2_rn(di * x[3 * gi + 2], 0.f);
            y8[gi] = yv;
        }
    }
    __syncthreads();
    for (int i = t; i < len; i += blockDim.x) {
        unsigned vv = buf[i];
        int pos = atomicAdd(&cur[vv >> 17], 1);   // LDS atomic
        packed[beg + pos] = vv & 0x1FFFF;         // plain src id, node-sorted
    }
    if (b == 0 && t == 0) rowptr[N] = E;
}

// ---- layer 1: node-parallel, 32 lanes/node gather y8 (0.8MB, L2-resident);
// writes fp16 g rows (64B/row).
__global__ void k_l1(const unsigned int* __restrict__ csr, const int* __restrict__ rowptr,
                     const uint2* __restrict__ y8, const float* __restrict__ dis,
                     const float* __restrict__ W1, const float* __restrict__ b1,
                     __half* __restrict__ g, int N) {
    int t = blockIdx.x * blockDim.x + threadIdx.x;
    int i = t >> 5, j = t & 31;
    if (i >= N) return;
    int beg = rowptr[i], end = rowptr[i + 1];
    float ax = 0.f, ay = 0.f, az = 0.f;
    for (int e = beg + j; e < end; e += 32) {
        uint2 v = y8[csr[e]];
        float2 fa = __half22float2(*(const __half2*)&v.x);
        float2 fb = __half22float2(*(const __half2*)&v.y);
        ax += fa.x; ay += fa.y; az += fb.x;
    }
#pragma unroll
    for (int m = 16; m >= 1; m >>= 1) {
        ax += __shfl_xor(ax, m, 32);
        ay += __shfl_xor(ay, m, 32);
        az += __shfl_xor(az, m, 32);
    }
    float di = dis[i];
    uint2 vs = y8[i];                                // self loop (pre-scaled)
    float2 sa = __half22float2(*(const __half2*)&vs.x);
    float2 sb = __half22float2(*(const __half2*)&vs.y);
    float a0 = di * (ax + sa.x);
    float a1 = di * (ay + sa.y);
    float a2 = di * (az + sb.x);
    float h = b1[j] + a0 * W1[j] + a1 * W1[32 + j] + a2 * W1[64 + j];
    g[(size_t)i * 32 + j] = __float2half(di * fmaxf(h, 0.f));
}

// unpack one uint2 (4 halves) and accumulate into 4 fp32 accumulators
__device__ __forceinline__ void acc4(float& c0, float& c1, float& c2, float& c3,
                                     uint2 r) {
    __half2 a = *(const __half2*)&r.x;
    __half2 b = *(const __half2*)&r.y;
    float2 fa = __half22float2(a);
    float2 fb = __half22float2(b);
    c0 += fa.x; c1 += fa.y; c2 += fb.x; c3 += fb.y;
}

// ---- layer 2 (+L3 projection): 8 lanes/node, lane j owns features 4j..4j+3.
// 16-edge unroll: 4x int4 csr + 16x 8B gathers per iteration — twice the
// loads in flight per vmcnt stall vs R16's 8 (latency-stall amortization).
// 4 accumulator banks; LDS W2/b2/W3 epilogue.
__global__ void k_l2(const unsigned int* __restrict__ csr, const int* __restrict__ rowptr,
                     const __half* __restrict__ g, const float* __restrict__ dis,
                     const float* __restrict__ W2, const float* __restrict__ b2,
                     const float* __restrict__ W3, float* __restrict__ q, int N) {
    __shared__ float sW2[1024];                      // 4KB: [32 in][32 out]
    __shared__ float sb2[32];
    __shared__ float sW3[32];
    int tid = threadIdx.x;
    ((float4*)sW2)[tid] = ((const float4*)W2)[tid];  // 256 thr x 16B = 4KB
    if (tid < 32) { sb2[tid] = b2[tid]; sW3[tid] = W3[tid]; }
    __syncthreads();
    int t = blockIdx.x * blockDim.x + tid;
    int i = t >> 3, j = t & 7;
    if (i >= N) return;
    int beg = rowptr[i], end = rowptr[i + 1];
    const uint2* g2 = (const uint2*)g;               // [N][8] x 8B slices
    float pa0 = 0.f, pa1 = 0.f, pa2 = 0.f, pa3 = 0.f;   // bank A
    float pb0 = 0.f, pb1 = 0.f, pb2 = 0.f, pb3 = 0.f;   // bank B
    float pc0 = 0.f, pc1 = 0.f, pc2 = 0.f, pc3 = 0.f;   // bank C
    float pd0 = 0.f, pd1 = 0.f, pd2 = 0.f, pd3 = 0.f;   // bank D
    int e = beg;
    // head-peel to 4-edge (16B) alignment for int4 csr loads
    for (; e < end && (e & 3); e++) {
        int s = (int)csr[e];
        uint2 r = g2[s * 8 + j];
        acc4(pa0, pa1, pa2, pa3, r);
    }
    // 16-edge unrolled main loop
    for (; e + 16 <= end; e += 16) {
        int4 ca = *(const int4*)(csr + e);
        int4 cb = *(const int4*)(csr + e + 4);
        int4 cc = *(const int4*)(csr + e + 8);
        int4 cd = *(const int4*)(csr + e + 12);
        uint2 r0  = g2[ca.x * 8 + j];
        uint2 r1  = g2[ca.y * 8 + j];
        uint2 r2  = g2[ca.z * 8 + j];
        uint2 r3  = g2[ca.w * 8 + j];
        uint2 r4  = g2[cb.x * 8 + j];
        uint2 r5  = g2[cb.y * 8 + j];
        uint2 r6  = g2[cb.z * 8 + j];
        uint2 r7  = g2[cb.w * 8 + j];
        uint2 r8  = g2[cc.x * 8 + j];
        uint2 r9  = g2[cc.y * 8 + j];
        uint2 r10 = g2[cc.z * 8 + j];
        uint2 r11 = g2[cc.w * 8 + j];
        uint2 r12 = g2[cd.x * 8 + j];
        uint2 r13 = g2[cd.y * 8 + j];
        uint2 r14 = g2[cd.z * 8 + j];
        uint2 r15 = g2[cd.w * 8 + j];
        acc4(pa0, pa1, pa2, pa3, r0);
        acc4(pb0, pb1, pb2, pb3, r1);
        acc4(pc0, pc1, pc2, pc3, r2);
        acc4(pd0, pd1, pd2, pd3, r3);
        acc4(pa0, pa1, pa2, pa3, r4);
        acc4(pb0, pb1, pb2, pb3, r5);
        acc4(pc0, pc1, pc2, pc3, r6);
        acc4(pd0, pd1, pd2, pd3, r7);
        acc4(pa0, pa1, pa2, pa3, r8);
        acc4(pb0, pb1, pb2, pb3, r9);
        acc4(pc0, pc1, pc2, pc3, r10);
        acc4(pd0, pd1, pd2, pd3, r11);
        acc4(pa0, pa1, pa2, pa3, r12);
        acc4(pb0, pb1, pb2, pb3, r13);
        acc4(pc0, pc1, pc2, pc3, r14);
        acc4(pd0, pd1, pd2, pd3, r15);
    }
    // 8-edge cleanup
    for (; e + 8 <= end; e += 8) {
        int4 ca = *(const int4*)(csr + e);
        int4 cb = *(const int4*)(csr + e + 4);
        uint2 r0 = g2[ca.x * 8 + j];
        uint2 r1 = g2[ca.y * 8 + j];
        uint2 r2 = g2[ca.z * 8 + j];
        uint2 r3 = g2[ca.w * 8 + j];
        uint2 r4 = g2[cb.x * 8 + j];
        uint2 r5 = g2[cb.y * 8 + j];
        uint2 r6 = g2[cb.z * 8 + j];
        uint2 r7 = g2[cb.w * 8 + j];
        acc4(pa0, pa1, pa2, pa3, r0);
        acc4(pb0, pb1, pb2, pb3, r1);
        acc4(pc0, pc1, pc2, pc3, r2);
        acc4(pd0, pd1, pd2, pd3, r3);
        acc4(pa0, pa1, pa2, pa3, r4);
        acc4(pb0, pb1, pb2, pb3, r5);
        acc4(pc0, pc1, pc2, pc3, r6);
        acc4(pd0, pd1, pd2, pd3, r7);
    }
    for (; e < end; e++) {
        int s = (int)csr[e];
        uint2 r = g2[s * 8 + j];
        acc4(pa0, pa1, pa2, pa3, r);
    }
    float c0 = (pa0 + pb0) + (pc0 + pd0);
    float c1 = (pa1 + pb1) + (pc1 + pd1);
    float c2 = (pa2 + pb2) + (pc2 + pd2);
    float c3 = (pa3 + pb3) + (pc3 + pd3);
    float di = dis[i];
    uint2 rs = g2[i * 8 + j];                        // self-loop slice
    float2 sa = __half22float2(*(const __half2*)&rs.x);
    float2 sb = __half22float2(*(const __half2*)&rs.y);
    float a0 = di * (c0 + sa.x);
    float a1 = di * (c1 + sa.y);
    float a2 = di * (c2 + sb.x);
    float a3 = di * (c3 + sb.y);
    // W2 matmul from LDS: lane j -> outputs m=4j..4j+3
    int m = 4 * j;
    float4 bo = *(const float4*)&sb2[m];
    float o0 = bo.x, o1 = bo.y, o2 = bo.z, o3 = bo.w;
#pragma unroll
    for (int kl = 0; kl < 8; kl++) {
        float x0 = __shfl(a0, kl, 8);                // a[4kl+0]
        float x1 = __shfl(a1, kl, 8);
        float x2 = __shfl(a2, kl, 8);
        float x3 = __shfl(a3, kl, 8);
        float4 w0 = *(const float4*)&sW2[(4 * kl + 0) * 32 + m];
        float4 w1 = *(const float4*)&sW2[(4 * kl + 1) * 32 + m];
        float4 w2 = *(const float4*)&sW2[(4 * kl + 2) * 32 + m];
        float4 w3 = *(const float4*)&sW2[(4 * kl + 3) * 32 + m];
        o0 = fmaf(x0, w0.x, fmaf(x1, w1.x, fmaf(x2, w2.x, fmaf(x3, w3.x, o0))));
        o1 = fmaf(x0, w0.y, fmaf(x1, w1.y, fmaf(x2, w2.y, fmaf(x3, w3.y, o1))));
        o2 = fmaf(x0, w0.z, fmaf(x1, w1.z, fmaf(x2, w2.z, fmaf(x3, w3.z, o2))));
        o3 = fmaf(x0, w0.w, fmaf(x1, w1.w, fmaf(x2, w2.w, fmaf(x3, w3.w, o3))));
    }
    float4 wv = *(const float4*)&sW3[m];
    float cc = fmaxf(o0, 0.f) * wv.x + fmaxf(o1, 0.f) * wv.y
             + fmaxf(o2, 0.f) * wv.z + fmaxf(o3, 0.f) * wv.w;
    cc += __shfl_xor(cc, 1, 8);
    cc += __shfl_xor(cc, 2, 8);
    cc += __shfl_xor(cc, 4, 8);
    if (j == 0) q[i] = di * cc;                      // q = dis * p
}

// ---- layer 3: node-parallel scalar q gathers (q 400KB, L2-resident)
__global__ void k_l3(const unsigned int* __restrict__ csr, const int* __restrict__ rowptr,
                     const float* __restrict__ q, const float* __restrict__ dis,
                     const float* __restrict__ b3, float* __restrict__ out, int N) {
    int t = blockIdx.x * blockDim.x + threadIdx.x;
    int i = t >> 5, j = t & 31;
    if (i >= N) return;
    int beg = rowptr[i], end = rowptr[i + 1];
    float acc = 0.f;
    for (int e = beg + j; e < end; e += 32)
        acc += q[csr[e]];
#pragma unroll
    for (int m = 16; m >= 1; m >>= 1)
        acc += __shfl_xor(acc, m, 32);
    if (j == 0) out[i] = dis[i] * (acc + q[i]) + b3[0];
}

extern "C" void kernel_launch(void* const* d_in, const int* in_sizes, int n_in,
                              void* d_out, int out_size, void* d_ws, size_t ws_size,
                              hipStream_t stream) {
    const float* x  = (const float*)d_in[0];
    const int*   ei = (const int*)d_in[1];
    const float* W1 = (const float*)d_in[2];
    const float* b1 = (const float*)d_in[3];
    const float* W2 = (const float*)d_in[4];
    const float* b2 = (const float*)d_in[5];
    const float* W3 = (const float*)d_in[6];
    const float* b3 = (const float*)d_in[7];
    float* out = (float*)d_out;

    int N = in_sizes[0] / 3;
    int E = in_sizes[1] / 2;
    const int* src = ei;
    const int* dst = ei + E;

    // workspace (all init done in-kernel; no memset needed), 256B-aligned carves
    char* w = (char*)d_ws;
#define CARVE(nbytes) w; w += (((size_t)(nbytes) + 255) & ~(size_t)255)
    int*   hist   = (int*)  CARVE((size_t)SB * NBKT * 4);   // 5.0 MB
    int*   btot   = (int*)  CARVE((size_t)MAXNB * 4);
    int*   bbase  = (int*)  CARVE((size_t)(MAXNB + 1) * 4);
    int*   rowptr = (int*)  CARVE((size_t)(N + 1) * 4);
    float* dis    = (float*)CARVE((size_t)N * 4);
    uint2* y8     = (uint2*)CARVE((size_t)N * 8);           // fp16 x4 per node
    __half* g     = (__half*)CARVE((size_t)N * 32 * 2);     // 6.4 MB fp16
    float* q      = (float*)CARVE((size_t)N * 4);
    unsigned int* packed = (unsigned int*)CARVE((size_t)E * 4);  // 25.6 MB
#undef CARVE

    k_hist <<<SB, BLK, 0, stream>>>(dst, hist, E);
    k_scanA<<<NBKT, BLK2, 0, stream>>>(hist, btot, NBKT);
    k_scanB<<<1, MAXNB, 0, stream>>>(btot, bbase, NBKT, E);
    k_bsort<<<SB, BLK2, 0, stream>>>(src, dst, hist, btot, bbase, packed, E);
    k_sort <<<NBKT, BLK2, 0, stream>>>(packed, bbase, x, dis, y8, rowptr, N, E);

    long long tn = (long long)N * 32;
    unsigned gn = (unsigned)((tn + BLK - 1) / BLK);
    long long tn8 = (long long)N * 8;
    unsigned gn8 = (unsigned)((tn8 + BLK - 1) / BLK);
    k_l1<<<gn,  BLK, 0, stream>>>(packed, rowptr, y8, dis, W1, b1, g, N);
    k_l2<<<gn8, BLK, 0, stream>>>(packed, rowptr, g, dis, W2, b2, W3, q, N);
    k_l3<<<gn,  BLK, 0, stream>>>(packed, rowptr, q, dis, b3, out, N);
}

// Round 15
// 316.540 us; speedup vs baseline: 1.0445x; 1.0256x over previous
//
#include <hip/hip_runtime.h>
#include <hip/hip_fp16.h>

// GCN 3->32->32->1, N=100K, E=6.4M (+self loops).
// R21/R22 verdict: k_l2 at HW floor (~72us, ~7cyc/CU/edge divergent
//   line-fill). Concurrency/requests/bytes/locality/dep-chains ALL
//   falsified (10 experiments). k_l2 frozen.
// R23: attack the ~190us of non-BW slack in preprocessing:
//   (1) k_sort count phase: 4 wave-pair sub-histograms (2KB) — LDS-atomic
//       contention 4x down; BUFSZ 9400 (mean+13.4sig) keeps 4 blocks/CU.
//   (2) k_bsort: CHUNK 4000->6400 (SB=1000) — phase-d runs 5.1->8.2 edges
//       (20->33B) cutting partial-line write amp; 3 blocks/CU (R19 proved
//       3 vs 4 neutral here).
//   (3) k_hist: 512 threads + 2 sub-histograms (6.3KB).
//   Falsifier: <5us total delta => slack is launch/dependency latency =>
//   fuse kernels (cooperative) or declare.
// Carried: fp16 g + fp16 y8, 16-edge k_l2 w/ LDS W2 epilogue, int4 csr,
//   fused k_sort, hist-row-differencing k_bsort, zero global atomics.

#define BLK 256
#define BLK2 512         // k_hist / k_bsort / k_sort / k_scanA block size
#define SB 1000          // chunks; SB*CHUNK == E exactly
#define CHUNK 6400
#define BKT 128          // nodes per bucket
#define NBKT 782         // ceil(100000/128)
#define MAXNB 1024       // scanB width >= NBKT
#define BUFSZ 9400       // k_sort bucket buffer (mean 8192 + 13.4 sigma)

// ---- pass 1: per-chunk histogram over dst buckets (2 sub-hists, int4)
__global__ void k_hist(const int* __restrict__ dst, int* __restrict__ hist, int E) {
    __shared__ int lh[2][NBKT];                   // 6.3 KB
    for (int b = threadIdx.x; b < 2 * NBKT; b += blockDim.x)
        ((int*)lh)[b] = 0;
    __syncthreads();
    int t = threadIdx.x;
    int sub = (t >> 8) & 1;                       // waves 0-3 vs 4-7
    int beg = blockIdx.x * CHUNK;
    int end = min(E, beg + CHUNK);
    int nq = (end - beg) >> 2;                    // full int4 quads
    const int4* d4 = (const int4*)(dst + beg);
    for (int i = t; i < nq; i += blockDim.x) {
        int4 d = d4[i];
        atomicAdd(&lh[sub][d.x >> 7], 1);
        atomicAdd(&lh[sub][d.y >> 7], 1);
        atomicAdd(&lh[sub][d.z >> 7], 1);
        atomicAdd(&lh[sub][d.w >> 7], 1);
    }
    for (int e = beg + (nq << 2) + t; e < end; e += blockDim.x)
        atomicAdd(&lh[sub][dst[e] >> 7], 1);
    __syncthreads();
    for (int b = t; b < NBKT; b += blockDim.x)
        hist[(size_t)blockIdx.x * NBKT + b] = lh[0][b] + lh[1][b];
}

// ---- scan A: per bucket, exclusive-scan its SB chunk-counts
// (512 threads x 2 guarded items = 1024 >= SB=1000)
__global__ void k_scanA(int* __restrict__ hist, int* __restrict__ btot, int NB) {
    int b = blockIdx.x, t = threadIdx.x;
    int base = t * 2;
    int v0 = (base + 0 < SB) ? hist[(size_t)(base + 0) * NB + b] : 0;
    int v1 = (base + 1 < SB) ? hist[(size_t)(base + 1) * NB + b] : 0;
    int s = v0 + v1;
    int lane = t & 63, w = t >> 6;
    int x = s;
#pragma unroll
    for (int off = 1; off < 64; off <<= 1) {
        int u = __shfl_up(x, off, 64);
        if (lane >= off) x += u;
    }
    __shared__ int wsum[8];
    if (lane == 63) wsum[w] = x;
    __syncthreads();
    int woff = 0;
    for (int k = 0; k < 8; k++) woff += (k < w) ? wsum[k] : 0;
    int run = woff + x - s;                       // exclusive prefix for item 0
    if (base + 0 < SB) hist[(size_t)(base + 0) * NB + b] = run;  run += v0;
    if (base + 1 < SB) hist[(size_t)(base + 1) * NB + b] = run;  run += v1;
    if (t == 511) btot[b] = run;
}

// ---- scan B: exclusive-scan bucket totals -> bucket base offsets
__global__ void k_scanB(const int* __restrict__ btot, int* __restrict__ bbase,
                        int NB, int E) {
    __shared__ int sh[MAXNB];
    int t = threadIdx.x;
    int v = (t < NB) ? btot[t] : 0;
    sh[t] = v;
    __syncthreads();
    for (int off = 1; off < MAXNB; off <<= 1) {
        int u = (t >= off) ? sh[t - off] : 0;
        __syncthreads();
        sh[t] += u;
        __syncthreads();
    }
    if (t < NB) bbase[t] = sh[t] - v;
    if (t == 0) bbase[NB] = E;
}

// ---- pass 2: LDS chunk-sort by bucket, full-lane sorted-order streaming.
// Chunk counts from hist-row differencing (scanA in-place prefixes).
// CHUNK 6400: phase-d runs avg 8.2 edges (33B) — less write amplification.
__global__ void k_bsort(const int* __restrict__ src, const int* __restrict__ dst,
                        const int* __restrict__ hist, const int* __restrict__ btot,
                        const int* __restrict__ bbase,
                        unsigned int* __restrict__ packed, int E) {
    __shared__ unsigned int bufB[CHUNK];          // 25.6 KB
    __shared__ unsigned short binarr2[CHUNK];     // 12.8 KB (bucket of sorted pos)
    __shared__ int cnt[NBKT];
    __shared__ int off[NBKT];
    __shared__ int cur[NBKT];
    __shared__ int gbase[NBKT];
    __shared__ int wsum[8];
    int t = threadIdx.x;
    int beg = blockIdx.x * CHUNK;
    int end = min(E, beg + CHUNK);
    int len = end - beg;
    int last = (blockIdx.x + 1 == gridDim.x);
    for (int b = t; b < NBKT; b += blockDim.x) {
        int my = hist[(size_t)blockIdx.x * NBKT + b];
        int nx = last ? btot[b] : hist[(size_t)(blockIdx.x + 1) * NBKT + b];
        cnt[b] = nx - my;
        gbase[b] = bbase[b] + my;
    }
    __syncthreads();
    // phase b: exclusive scan of 782 counts (2 items/thread, shfl, 8 waves)
    {
        int base = t * 2;
        int v0 = (base + 0 < NBKT) ? cnt[base + 0] : 0;
        int v1 = (base + 1 < NBKT) ? cnt[base + 1] : 0;
        int s = v0 + v1;
        int lane = t & 63, w = t >> 6;
        int x = s;
#pragma unroll
        for (int o = 1; o < 64; o <<= 1) {
            int u = __shfl_up(x, o, 64);
            if (lane >= o) x += u;
        }
        if (lane == 63) wsum[w] = x;
        __syncthreads();
        int woff = 0;
        for (int k = 0; k < 8; k++) woff += (k < w) ? wsum[k] : 0;
        int run = woff + x - s;
        if (base + 0 < NBKT) { off[base + 0] = run; cur[base + 0] = run; } run += v0;
        if (base + 1 < NBKT) { off[base + 1] = run; cur[base + 1] = run; } run += v1;
    }
    __syncthreads();
    // phase c: permute into bucket-grouped order
    for (int i = t; i < len; i += blockDim.x) {
        int d = dst[beg + i];
        int s = src[beg + i];
        int b = d >> 7;
        int pos = atomicAdd(&cur[b], 1);
        bufB[pos] = (unsigned)s | ((unsigned)(d & 127) << 17);
        binarr2[pos] = (unsigned short)b;
    }
    __syncthreads();
    // phase d: full-lane sorted-order write (runs are dest-contiguous)
    for (int i = t; i < len; i += blockDim.x) {
        int b = binarr2[i];
        packed[gbase[b] + i - off[b]] = bufB[i];
    }
}

// ---- fused: per-bucket 128-bin count (4 sub-hists) + scan + dis/y8/rowptr
// + in-place node sort. 512 threads, fused load+count. y stored as 4 fp16.
__global__ void k_sort(unsigned int* __restrict__ packed, const int* __restrict__ bbase,
                       const float* __restrict__ x, float* __restrict__ dis,
                       uint2* __restrict__ y8, int* __restrict__ rowptr, int N, int E) {
    __shared__ unsigned int buf[BUFSZ];           // 36.7 KB
    __shared__ int cnt4[4][BKT];                  // 2 KB (wave-pair private)
    __shared__ int cur[BKT];
    __shared__ int wsum[2];
    int b = blockIdx.x, t = threadIdx.x;
    int beg = bbase[b], end = bbase[b + 1];
    int len = end - beg;
    for (int k = t; k < 4 * BKT; k += blockDim.x) ((int*)cnt4)[k] = 0;
    __syncthreads();
    int sub = (t >> 7) & 3;                       // wave pairs 0..3
    // fused: load bucket into LDS + count bins in one pass (4x less contention)
    for (int i = t; i < len; i += blockDim.x) {
        unsigned v = packed[beg + i];
        buf[i] = v;
        atomicAdd(&cnt4[sub][v >> 17], 1);
    }
    __syncthreads();
    // exclusive scan over 128 bins (threads 0..127, 2 waves)
    int v0 = 0, xs = 0;
    if (t < BKT) {
        v0 = cnt4[0][t] + cnt4[1][t] + cnt4[2][t] + cnt4[3][t];
        xs = v0;
#pragma unroll
        for (int o = 1; o < 64; o <<= 1) {
            int u = __shfl_up(xs, o, 64);
            if ((t & 63) >= o) xs += u;
        }
        if ((t & 63) == 63) wsum[t >> 6] = xs;
    }
    __syncthreads();
    if (t < BKT) {
        int woff = (t >= 64) ? wsum[0] : 0;
        int excl = woff + xs - v0;
        cur[t] = excl;
        int gi = b * BKT + t;
        if (gi < N) {
            rowptr[gi] = beg + excl;
            float di = rsqrtf((float)v0 + 1.0f);  // + self loop
            dis[gi] = di;
            uint2 yv;
            *(__half2*)&yv.x = __floats2half2_rn(di * x[3 * gi + 0],
                                                 di * x[3 * gi + 1]);
            *(__half2*)&yv.y = __floats2half2_rn(di * x[3 * gi + 2], 0.f);
            y8[gi] = yv;
        }
    }
    __syncthreads();
    for (int i = t; i < len; i += blockDim.x) {
        unsigned vv = buf[i];
        int pos = atomicAdd(&cur[vv >> 17], 1);   // LDS atomic
        packed[beg + pos] = vv & 0x1FFFF;         // plain src id, node-sorted
    }
    if (b == 0 && t == 0) rowptr[N] = E;
}

// ---- layer 1: node-parallel, 32 lanes/node gather y8 (0.8MB, L2-resident);
// writes fp16 g rows (64B/row).
__global__ void k_l1(const unsigned int* __restrict__ csr, const int* __restrict__ rowptr,
                     const uint2* __restrict__ y8, const float* __restrict__ dis,
                     const float* __restrict__ W1, const float* __restrict__ b1,
                     __half* __restrict__ g, int N) {
    int t = blockIdx.x * blockDim.x + threadIdx.x;
    int i = t >> 5, j = t & 31;
    if (i >= N) return;
    int beg = rowptr[i], end = rowptr[i + 1];
    float ax = 0.f, ay = 0.f, az = 0.f;
    for (int e = beg + j; e < end; e += 32) {
        uint2 v = y8[csr[e]];
        float2 fa = __half22float2(*(const __half2*)&v.x);
        float2 fb = __half22float2(*(const __half2*)&v.y);
        ax += fa.x; ay += fa.y; az += fb.x;
    }
#pragma unroll
    for (int m = 16; m >= 1; m >>= 1) {
        ax += __shfl_xor(ax, m, 32);
        ay += __shfl_xor(ay, m, 32);
        az += __shfl_xor(az, m, 32);
    }
    float di = dis[i];
    uint2 vs = y8[i];                                // self loop (pre-scaled)
    float2 sa = __half22float2(*(const __half2*)&vs.x);
    float2 sb = __half22float2(*(const __half2*)&vs.y);
    float a0 = di * (ax + sa.x);
    float a1 = di * (ay + sa.y);
    float a2 = di * (az + sb.x);
    float h = b1[j] + a0 * W1[j] + a1 * W1[32 + j] + a2 * W1[64 + j];
    g[(size_t)i * 32 + j] = __float2half(di * fmaxf(h, 0.f));
}

// unpack one uint2 (4 halves) and accumulate into 4 fp32 accumulators
__device__ __forceinline__ void acc4(float& c0, float& c1, float& c2, float& c3,
                                     uint2 r) {
    __half2 a = *(const __half2*)&r.x;
    __half2 b = *(const __half2*)&r.y;
    float2 fa = __half22float2(a);
    float2 fb = __half22float2(b);
    c0 += fa.x; c1 += fa.y; c2 += fb.x; c3 += fb.y;
}

// ---- layer 2 (+L3 projection): 8 lanes/node, lane j owns features 4j..4j+3.
// [AT HW FLOOR ~72us — 10 experiments closed; do not touch]
__global__ void k_l2(const unsigned int* __restrict__ csr, const int* __restrict__ rowptr,
                     const __half* __restrict__ g, const float* __restrict__ dis,
                     const float* __restrict__ W2, const float* __restrict__ b2,
                     const float* __restrict__ W3, float* __restrict__ q, int N) {
    __shared__ float sW2[1024];                      // 4KB: [32 in][32 out]
    __shared__ float sb2[32];
    __shared__ float sW3[32];
    int tid = threadIdx.x;
    ((float4*)sW2)[tid] = ((const float4*)W2)[tid];  // 256 thr x 16B = 4KB
    if (tid < 32) { sb2[tid] = b2[tid]; sW3[tid] = W3[tid]; }
    __syncthreads();
    int t = blockIdx.x * blockDim.x + tid;
    int i = t >> 3, j = t & 7;
    if (i >= N) return;
    int beg = rowptr[i], end = rowptr[i + 1];
    const uint2* g2 = (const uint2*)g;               // [N][8] x 8B slices
    float pa0 = 0.f, pa1 = 0.f, pa2 = 0.f, pa3 = 0.f;   // bank A
    float pb0 = 0.f, pb1 = 0.f, pb2 = 0.f, pb3 = 0.f;   // bank B
    float pc0 = 0.f, pc1 = 0.f, pc2 = 0.f, pc3 = 0.f;   // bank C
    float pd0 = 0.f, pd1 = 0.f, pd2 = 0.f, pd3 = 0.f;   // bank D
    int e = beg;
    // head-peel to 4-edge (16B) alignment for int4 csr loads
    for (; e < end && (e & 3); e++) {
        int s = (int)csr[e];
        uint2 r = g2[s * 8 + j];
        acc4(pa0, pa1, pa2, pa3, r);
    }
    // 16-edge unrolled main loop
    for (; e + 16 <= end; e += 16) {
        int4 ca = *(const int4*)(csr + e);
        int4 cb = *(const int4*)(csr + e + 4);
        int4 cc = *(const int4*)(csr + e + 8);
        int4 cd = *(const int4*)(csr + e + 12);
        uint2 r0  = g2[ca.x * 8 + j];
        uint2 r1  = g2[ca.y * 8 + j];
        uint2 r2  = g2[ca.z * 8 + j];
        uint2 r3  = g2[ca.w * 8 + j];
        uint2 r4  = g2[cb.x * 8 + j];
        uint2 r5  = g2[cb.y * 8 + j];
        uint2 r6  = g2[cb.z * 8 + j];
        uint2 r7  = g2[cb.w * 8 + j];
        uint2 r8  = g2[cc.x * 8 + j];
        uint2 r9  = g2[cc.y * 8 + j];
        uint2 r10 = g2[cc.z * 8 + j];
        uint2 r11 = g2[cc.w * 8 + j];
        uint2 r12 = g2[cd.x * 8 + j];
        uint2 r13 = g2[cd.y * 8 + j];
        uint2 r14 = g2[cd.z * 8 + j];
        uint2 r15 = g2[cd.w * 8 + j];
        acc4(pa0, pa1, pa2, pa3, r0);
        acc4(pb0, pb1, pb2, pb3, r1);
        acc4(pc0, pc1, pc2, pc3, r2);
        acc4(pd0, pd1, pd2, pd3, r3);
        acc4(pa0, pa1, pa2, pa3, r4);
        acc4(pb0, pb1, pb2, pb3, r5);
        acc4(pc0, pc1, pc2, pc3, r6);
        acc4(pd0, pd1, pd2, pd3, r7);
        acc4(pa0, pa1, pa2, pa3, r8);
        acc4(pb0, pb1, pb2, pb3, r9);
        acc4(pc0, pc1, pc2, pc3, r10);
        acc4(pd0, pd1, pd2, pd3, r11);
        acc4(pa0, pa1, pa2, pa3, r12);
        acc4(pb0, pb1, pb2, pb3, r13);
        acc4(pc0, pc1, pc2, pc3, r14);
        acc4(pd0, pd1, pd2, pd3, r15);
    }
    // 8-edge cleanup
    for (; e + 8 <= end; e += 8) {
        int4 ca = *(const int4*)(csr + e);
        int4 cb = *(const int4*)(csr + e + 4);
        uint2 r0 = g2[ca.x * 8 + j];
        uint2 r1 = g2[ca.y * 8 + j];
        uint2 r2 = g2[ca.z * 8 + j];
        uint2 r3 = g2[ca.w * 8 + j];
        uint2 r4 = g2[cb.x * 8 + j];
        uint2 r5 = g2[cb.y * 8 + j];
        uint2 r6 = g2[cb.z * 8 + j];
        uint2 r7 = g2[cb.w * 8 + j];
        acc4(pa0, pa1, pa2, pa3, r0);
        acc4(pb0, pb1, pb2, pb3, r1);
        acc4(pc0, pc1, pc2, pc3, r2);
        acc4(pd0, pd1, pd2, pd3, r3);
        acc4(pa0, pa1, pa2, pa3, r4);
        acc4(pb0, pb1, pb2, pb3, r5);
        acc4(pc0, pc1, pc2, pc3, r6);
        acc4(pd0, pd1, pd2, pd3, r7);
    }
    for (; e < end; e++) {
        int s = (int)csr[e];
        uint2 r = g2[s * 8 + j];
        acc4(pa0, pa1, pa2, pa3, r);
    }
    float c0 = (pa0 + pb0) + (pc0 + pd0);
    float c1 = (pa1 + pb1) + (pc1 + pd1);
    float c2 = (pa2 + pb2) + (pc2 + pd2);
    float c3 = (pa3 + pb3) + (pc3 + pd3);
    float di = dis[i];
    uint2 rs = g2[i * 8 + j];                        // self-loop slice
    float2 sa = __half22float2(*(const __half2*)&rs.x);
    float2 sb = __half22float2(*(const __half2*)&rs.y);
    float a0 = di * (c0 + sa.x);
    float a1 = di * (c1 + sa.y);
    float a2 = di * (c2 + sb.x);
    float a3 = di * (c3 + sb.y);
    // W2 matmul from LDS: lane j -> outputs m=4j..4j+3
    int m = 4 * j;
    float4 bo = *(const float4*)&sb2[m];
    float o0 = bo.x, o1 = bo.y, o2 = bo.z, o3 = bo.w;
#pragma unroll
    for (int kl = 0; kl < 8; kl++) {
        float x0 = __shfl(a0, kl, 8);                // a[4kl+0]
        float x1 = __shfl(a1, kl, 8);
        float x2 = __shfl(a2, kl, 8);
        float x3 = __shfl(a3, kl, 8);
        float4 w0 = *(const float4*)&sW2[(4 * kl + 0) * 32 + m];
        float4 w1 = *(const float4*)&sW2[(4 * kl + 1) * 32 + m];
        float4 w2 = *(const float4*)&sW2[(4 * kl + 2) * 32 + m];
        float4 w3 = *(const float4*)&sW2[(4 * kl + 3) * 32 + m];
        o0 = fmaf(x0, w0.x, fmaf(x1, w1.x, fmaf(x2, w2.x, fmaf(x3, w3.x, o0))));
        o1 = fmaf(x0, w0.y, fmaf(x1, w1.y, fmaf(x2, w2.y, fmaf(x3, w3.y, o1))));
        o2 = fmaf(x0, w0.z, fmaf(x1, w1.z, fmaf(x2, w2.z, fmaf(x3, w3.z, o2))));
        o3 = fmaf(x0, w0.w, fmaf(x1, w1.w, fmaf(x2, w2.w, fmaf(x3, w3.w, o3))));
    }
    float4 wv = *(const float4*)&sW3[m];
    float cc = fmaxf(o0, 0.f) * wv.x + fmaxf(o1, 0.f) * wv.y
             + fmaxf(o2, 0.f) * wv.z + fmaxf(o3, 0.f) * wv.w;
    cc += __shfl_xor(cc, 1, 8);
    cc += __shfl_xor(cc, 2, 8);
    cc += __shfl_xor(cc, 4, 8);
    if (j == 0) q[i] = di * cc;                      // q = dis * p
}

// ---- layer 3: node-parallel scalar q gathers (q 400KB, L2-resident)
__global__ void k_l3(const unsigned int* __restrict__ csr, const int* __restrict__ rowptr,
                     const float* __restrict__ q, const float* __restrict__ dis,
                     const float* __restrict__ b3, float* __restrict__ out, int N) {
    int t = blockIdx.x * blockDim.x + threadIdx.x;
    int i = t >> 5, j = t & 31;
    if (i >= N) return;
    int beg = rowptr[i], end = rowptr[i + 1];
    float acc = 0.f;
    for (int e = beg + j; e < end; e += 32)
        acc += q[csr[e]];
#pragma unroll
    for (int m = 16; m >= 1; m >>= 1)
        acc += __shfl_xor(acc, m, 32);
    if (j == 0) out[i] = dis[i] * (acc + q[i]) + b3[0];
}

extern "C" void kernel_launch(void* const* d_in, const int* in_sizes, int n_in,
                              void* d_out, int out_size, void* d_ws, size_t ws_size,
                              hipStream_t stream) {
    const float* x  = (const float*)d_in[0];
    const int*   ei = (const int*)d_in[1];
    const float* W1 = (const float*)d_in[2];
    const float* b1 = (const float*)d_in[3];
    const float* W2 = (const float*)d_in[4];
    const float* b2 = (const float*)d_in[5];
    const float* W3 = (const float*)d_in[6];
    const float* b3 = (const float*)d_in[7];
    float* out = (float*)d_out;

    int N = in_sizes[0] / 3;
    int E = in_sizes[1] / 2;
    const int* src = ei;
    const int* dst = ei + E;

    // workspace (all init done in-kernel; no memset needed), 256B-aligned carves
    char* w = (char*)d_ws;
#define CARVE(nbytes) w; w += (((size_t)(nbytes) + 255) & ~(size_t)255)
    int*   hist   = (int*)  CARVE((size_t)SB * NBKT * 4);   // 3.1 MB
    int*   btot   = (int*)  CARVE((size_t)MAXNB * 4);
    int*   bbase  = (int*)  CARVE((size_t)(MAXNB + 1) * 4);
    int*   rowptr = (int*)  CARVE((size_t)(N + 1) * 4);
    float* dis    = (float*)CARVE((size_t)N * 4);
    uint2* y8     = (uint2*)CARVE((size_t)N * 8);           // fp16 x4 per node
    __half* g     = (__half*)CARVE((size_t)N * 32 * 2);     // 6.4 MB fp16
    float* q      = (float*)CARVE((size_t)N * 4);
    unsigned int* packed = (unsigned int*)CARVE((size_t)E * 4);  // 25.6 MB
#undef CARVE

    k_hist <<<SB, BLK2, 0, stream>>>(dst, hist, E);
    k_scanA<<<NBKT, BLK2, 0, stream>>>(hist, btot, NBKT);
    k_scanB<<<1, MAXNB, 0, stream>>>(btot, bbase, NBKT, E);
    k_bsort<<<SB, BLK2, 0, stream>>>(src, dst, hist, btot, bbase, packed, E);
    k_sort <<<NBKT, BLK2, 0, stream>>>(packed, bbase, x, dis, y8, rowptr, N, E);

    long long tn = (long long)N * 32;
    unsigned gn = (unsigned)((tn + BLK - 1) / BLK);
    long long tn8 = (long long)N * 8;
    unsigned gn8 = (unsigned)((tn8 + BLK - 1) / BLK);
    k_l1<<<gn,  BLK, 0, stream>>>(packed, rowptr, y8, dis, W1, b1, g, N);
    k_l2<<<gn8, BLK, 0, stream>>>(packed, rowptr, g, dis, W2, b2, W3, q, N);
    k_l3<<<gn,  BLK, 0, stream>>>(packed, rowptr, q, dis, b3, out, N);
}